// Round 1
// baseline (8976.331 us; speedup 1.0000x reference)
//
#include <hip/hip_runtime.h>
#include <math.h>

#define NN   16384      // total nodes
#define NE   262144     // edges (no self loops)
#define NB   64         // graphs
#define SEQT 256        // nodes per graph (= seq len)
#define DEP  64
#define DOUT 256        // = HID
#define G3   768        // 3*HID

// ---------------------------------------------------------------------------
// degree / CSR build
// ---------------------------------------------------------------------------
__global__ void k_init_deg(int* deg) {
    int i = blockIdx.x * 256 + threadIdx.x;
    if (i < NN) deg[i] = 1;                       // self loop
}

__global__ void k_count(const int* __restrict__ ei, int* deg) {
    int e = blockIdx.x * 256 + threadIdx.x;
    if (e < NE) atomicAdd(&deg[ei[NE + e]], 1);   // col = dst
}

__global__ __launch_bounds__(1024) void k_scan_offs(const int* __restrict__ deg,
                                                    int* __restrict__ offs,
                                                    float* __restrict__ dinv) {
    __shared__ int lds[1024];
    const int tid = threadIdx.x;
    const int v0 = tid * 16;
    int loc[16];
    int s = 0;
#pragma unroll
    for (int i = 0; i < 16; ++i) {
        int d = deg[v0 + i];
        loc[i] = s;
        s += d - 1;                               // real in-edges only
        dinv[v0 + i] = rsqrtf((float)d);
    }
    lds[tid] = s;
    __syncthreads();
    for (int off = 1; off < 1024; off <<= 1) {
        int x = (tid >= off) ? lds[tid - off] : 0;
        __syncthreads();
        lds[tid] += x;
        __syncthreads();
    }
    int base = lds[tid] - s;                      // exclusive prefix of this thread
#pragma unroll
    for (int i = 0; i < 16; ++i) offs[v0 + i] = base + loc[i];
}

__global__ void k_fill(const int* __restrict__ ei, const int* __restrict__ offs,
                       int* cursor, int* __restrict__ eidx) {
    int e = blockIdx.x * 256 + threadIdx.x;
    if (e < NE) {
        int c = ei[NE + e];
        int pos = offs[c] + atomicAdd(&cursor[c], 1);
        eidx[pos] = e;
    }
}

__global__ void k_bself(const float* __restrict__ WB, float* Bself) {
    int f = threadIdx.x;                          // 256 threads
    float s = 0.f;
#pragma unroll
    for (int d = 0; d < DEP; ++d) s += WB[f * DEP + d];
    Bself[f] = s;
}

// ---------------------------------------------------------------------------
// generic fp32 GEMM:  C[M,N] = A[M,256] @ W[N,256]^T (+ bias[N])
// 128x128 tile, 8x8 micro, BK=8, 256 threads
// ---------------------------------------------------------------------------
__global__ __launch_bounds__(256) void k_gemm(const float* __restrict__ A,
                                              const float* __restrict__ W,
                                              const float* __restrict__ bias,
                                              float* __restrict__ C,
                                              int M, int N) {
    __shared__ float As[8][132];
    __shared__ float Ws[8][132];
    const int tid = threadIdx.x;
    const int m0 = blockIdx.x * 128;
    const int n0 = blockIdx.y * 128;
    const int lr = tid >> 1;                      // 0..127
    const int lk = (tid & 1) * 4;                 // 0 or 4
    const int tm = tid & 15, tn = tid >> 4;

    float acc[8][8];
#pragma unroll
    for (int i = 0; i < 8; ++i)
#pragma unroll
        for (int j = 0; j < 8; ++j) acc[i][j] = 0.f;

    for (int k0 = 0; k0 < 256; k0 += 8) {
        float4 av = *(const float4*)&A[(size_t)(m0 + lr) * 256 + k0 + lk];
        float4 wv = *(const float4*)&W[(size_t)(n0 + lr) * 256 + k0 + lk];
        As[lk + 0][lr] = av.x; As[lk + 1][lr] = av.y;
        As[lk + 2][lr] = av.z; As[lk + 3][lr] = av.w;
        Ws[lk + 0][lr] = wv.x; Ws[lk + 1][lr] = wv.y;
        Ws[lk + 2][lr] = wv.z; Ws[lk + 3][lr] = wv.w;
        __syncthreads();
#pragma unroll
        for (int kk = 0; kk < 8; ++kk) {
            float a[8], b[8];
            *(float4*)&a[0] = *(const float4*)&As[kk][tm * 8];
            *(float4*)&a[4] = *(const float4*)&As[kk][tm * 8 + 4];
            *(float4*)&b[0] = *(const float4*)&Ws[kk][tn * 8];
            *(float4*)&b[4] = *(const float4*)&Ws[kk][tn * 8 + 4];
#pragma unroll
            for (int i = 0; i < 8; ++i)
#pragma unroll
                for (int j = 0; j < 8; ++j)
                    acc[i][j] = fmaf(a[i], b[j], acc[i][j]);
        }
        __syncthreads();
    }

    float bv[8];
#pragma unroll
    for (int j = 0; j < 8; ++j) bv[j] = bias ? bias[n0 + tn * 8 + j] : 0.f;
#pragma unroll
    for (int i = 0; i < 8; ++i) {
        int m = m0 + tm * 8 + i;
        float4 o0, o1;
        o0.x = acc[i][0] + bv[0]; o0.y = acc[i][1] + bv[1];
        o0.z = acc[i][2] + bv[2]; o0.w = acc[i][3] + bv[3];
        o1.x = acc[i][4] + bv[4]; o1.y = acc[i][5] + bv[5];
        o1.z = acc[i][6] + bv[6]; o1.w = acc[i][7] + bv[7];
        *(float4*)&C[(size_t)m * N + n0 + tn * 8]     = o0;
        *(float4*)&C[(size_t)m * N + n0 + tn * 8 + 4] = o1;
    }
}

// ---------------------------------------------------------------------------
// GCN gather: one WG (256 thr) per node.  WB row in registers (fused Be).
// ---------------------------------------------------------------------------
__global__ __launch_bounds__(256) void k_gcn(const float* __restrict__ Ax,
                                             const float* __restrict__ WB,
                                             const float* __restrict__ edge_attr,
                                             const int* __restrict__ ei,
                                             const int* __restrict__ eidx,
                                             const int* __restrict__ offs,
                                             const int* __restrict__ deg,
                                             const float* __restrict__ dinv,
                                             const float* __restrict__ Bself,
                                             const float* __restrict__ gcn_bias,
                                             float* __restrict__ node) {
    const int v = blockIdx.x;
    const int f = threadIdx.x;

    float wb[64];
#pragma unroll
    for (int d4 = 0; d4 < 16; ++d4) {
        float4 t = *(const float4*)&WB[f * DEP + d4 * 4];
        wb[d4 * 4 + 0] = t.x; wb[d4 * 4 + 1] = t.y;
        wb[d4 * 4 + 2] = t.z; wb[d4 * 4 + 3] = t.w;
    }

    __shared__ float ea[2][64];
    __shared__ int   src_s[2];
    const int base = offs[v];
    const int cnt  = deg[v] - 1;
    const float dv = dinv[v];
    float acc = 0.f;

    if (cnt > 0) {
        if (f < 64) {
            int e0 = eidx[base];
            ea[0][f] = edge_attr[(size_t)e0 * DEP + f];
            if (f == 0) src_s[0] = ei[e0];
        }
        __syncthreads();
        for (int i = 0; i < cnt; ++i) {
            int cur = i & 1;
            if (i + 1 < cnt && f < 64) {
                int e1 = eidx[base + i + 1];
                ea[cur ^ 1][f] = edge_attr[(size_t)e1 * DEP + f];
                if (f == 0) src_s[cur ^ 1] = ei[e1];
            }
            int s = src_s[cur];
            float be = 0.f;
#pragma unroll
            for (int d = 0; d < 64; ++d) be = fmaf(wb[d], ea[cur][d], be);
            float ax = Ax[(size_t)s * DOUT + f];
            acc = fmaf(dinv[s] * dv, tanhf(ax * be), acc);
            __syncthreads();
        }
    }
    // self loop: norm = dinv[v]^2, Be = rowsum(WB)
    acc += dv * dv * tanhf(Ax[(size_t)v * DOUT + f] * Bself[f]);
    node[(size_t)v * DOUT + f] = tanhf(acc / (float)(cnt + 1) + gcn_bias[f]);
}

// ---------------------------------------------------------------------------
// GRU scan: 256 WGs = 64 graphs x 4 row-parts.  w_hh slice register-resident.
// Per-step cross-WG h exchange via agent atomics + release/acquire counter.
// ---------------------------------------------------------------------------
__global__ __launch_bounds__(256, 2) void k_gru_scan(const float* __restrict__ xp,
                                                     const float* __restrict__ w_hh,
                                                     const float* __restrict__ b_hh,
                                                     float* __restrict__ y,
                                                     float* __restrict__ hT,
                                                     float* h_buf,           // [2][64][256]
                                                     unsigned int* ctr) {    // [64]
    const int tid = threadIdx.x;
    const int wg  = blockIdx.x;
    // co-locate a graph's 4 WGs on one XCD (heuristic only)
    const int xcd = wg & 7, idx = wg >> 3;
    const int p = idx & 3;                    // row part: j in [64p, 64p+64)
    const int b = (xcd << 3) | (idx >> 2);    // graph
    const int c = tid & 15;                   // col group: cols {c+16k}
    const int q = tid >> 4;                   // owns rows [12q,12q+12) of 192

    // load weight slice into registers: rows rr = gate*64+jj (gate=rr/64)
    float w[12][16];
#pragma unroll
    for (int i = 0; i < 12; ++i) {
        int rr = q * 12 + i;
        int gate = rr >> 6, jj = rr & 63;
        int grow = gate * 256 + p * 64 + jj;
#pragma unroll
        for (int kk = 0; kk < 16; ++kk)
            w[i][kk] = w_hh[grow * 256 + c + 16 * kk];
    }
    float bhr = 0.f, bhz = 0.f, bhn = 0.f;
    if (tid < 64) {
        int j = p * 64 + tid;
        bhr = b_hh[j]; bhz = b_hh[256 + j]; bhn = b_hh[512 + j];
    }

    __shared__ float gh[192];

    for (int t = 0; t < SEQT; ++t) {
        const int rb = t & 1, wbuf = rb ^ 1;
        float* hsrc = h_buf + (rb * NB + b) * 256;
        float hreg[16];
#pragma unroll
        for (int kk = 0; kk < 16; ++kk)
            hreg[kk] = __hip_atomic_load(&hsrc[c + 16 * kk], __ATOMIC_RELAXED,
                                         __HIP_MEMORY_SCOPE_AGENT);
        float h_old = 0.f;
        if (tid < 64)
            h_old = __hip_atomic_load(&hsrc[p * 64 + tid], __ATOMIC_RELAXED,
                                      __HIP_MEMORY_SCOPE_AGENT);
        float acc[12];
#pragma unroll
        for (int i = 0; i < 12; ++i) {
            float s = 0.f;
#pragma unroll
            for (int kk = 0; kk < 16; ++kk) s = fmaf(w[i][kk], hreg[kk], s);
            acc[i] = s;
        }
        // reduce across the 16 col-groups (lane bits 0..3)
#pragma unroll
        for (int m = 1; m < 16; m <<= 1) {
#pragma unroll
            for (int i = 0; i < 12; ++i) acc[i] += __shfl_xor(acc[i], m, 64);
        }
        if (c == 0) {
#pragma unroll
            for (int i = 0; i < 12; ++i) gh[q * 12 + i] = acc[i];
        }
        __syncthreads();
        if (tid < 64) {
            int j = p * 64 + tid;
            int m = b * SEQT + t;
            float ghr = gh[tid] + bhr;
            float ghz = gh[64 + tid] + bhz;
            float ghn = gh[128 + tid] + bhn;
            float xr = xp[(size_t)m * G3 + j];
            float xz = xp[(size_t)m * G3 + 256 + j];
            float xn = xp[(size_t)m * G3 + 512 + j];
            float r = 1.f / (1.f + __expf(-(xr + ghr)));
            float z = 1.f / (1.f + __expf(-(xz + ghz)));
            float n = tanhf(xn + r * ghn);
            float hn = (1.f - z) * n + z * h_old;
            y[(size_t)m * DOUT + j] = hn;
            __hip_atomic_store(&h_buf[(wbuf * NB + b) * 256 + j], hn,
                               __ATOMIC_RELAXED, __HIP_MEMORY_SCOPE_AGENT);
            if (t == SEQT - 1) hT[b * 256 + j] = hn;
        }
        __syncthreads();
        if (tid == 0) {
            __hip_atomic_fetch_add(&ctr[b], 1u, __ATOMIC_RELEASE,
                                   __HIP_MEMORY_SCOPE_AGENT);
            unsigned target = 4u * (unsigned)(t + 1);
            while (__hip_atomic_load(&ctr[b], __ATOMIC_ACQUIRE,
                                     __HIP_MEMORY_SCOPE_AGENT) < target)
                __builtin_amdgcn_s_sleep(2);
        }
        __syncthreads();
    }
}

// ---------------------------------------------------------------------------
// pooling + linear + softmax: one WG per graph
// ---------------------------------------------------------------------------
__global__ __launch_bounds__(256) void k_final(const float* __restrict__ y2,
                                               const float* __restrict__ hT,
                                               const float* __restrict__ lin_W,
                                               const float* __restrict__ lin_b,
                                               float* __restrict__ out) {
    __shared__ float pool[1280];
    __shared__ float red[2][256];
    const int b = blockIdx.x, j = threadIdx.x;
    float mx = -1e30f, sm = 0.f;
    for (int t = 0; t < SEQT; ++t) {
        float v = y2[((size_t)(b * SEQT + t)) * DOUT + j];
        mx = fmaxf(mx, v);
        sm += v;
    }
    pool[j]        = hT[b * 256 + j];
    pool[256 + j]  = hT[16384 + b * 256 + j];
    pool[512 + j]  = hT[32768 + b * 256 + j];
    pool[768 + j]  = mx;
    pool[1024 + j] = sm * (1.f / 256.f);
    __syncthreads();
    float p0 = 0.f, p1 = 0.f;
    for (int i = j; i < 1280; i += 256) {
        float pv = pool[i];
        p0 = fmaf(lin_W[i], pv, p0);
        p1 = fmaf(lin_W[1280 + i], pv, p1);
    }
    red[0][j] = p0; red[1][j] = p1;
    __syncthreads();
    if (j == 0) {
        float l0 = lin_b[0], l1 = lin_b[1];
        for (int i = 0; i < 256; ++i) { l0 += red[0][i]; l1 += red[1][i]; }
        float m = fmaxf(l0, l1);
        float e0 = __expf(l0 - m), e1 = __expf(l1 - m);
        float s = e0 + e1;
        out[b * 2 + 0] = e0 / s;
        out[b * 2 + 1] = e1 / s;
    }
}

// ---------------------------------------------------------------------------
extern "C" void kernel_launch(void* const* d_in, const int* in_sizes, int n_in,
                              void* d_out, int out_size, void* d_ws, size_t ws_size,
                              hipStream_t stream) {
    const float* x         = (const float*)d_in[0];
    const float* edge_attr = (const float*)d_in[1];
    const int*   ei        = (const int*)d_in[2];
    const float* WA        = (const float*)d_in[3];
    const float* WB        = (const float*)d_in[4];
    const float* gcn_bias  = (const float*)d_in[5];
    const float* w_ih[3] = {(const float*)d_in[6],  (const float*)d_in[10], (const float*)d_in[14]};
    const float* w_hh[3] = {(const float*)d_in[7],  (const float*)d_in[11], (const float*)d_in[15]};
    const float* b_ih[3] = {(const float*)d_in[8],  (const float*)d_in[12], (const float*)d_in[16]};
    const float* b_hh[3] = {(const float*)d_in[9],  (const float*)d_in[13], (const float*)d_in[17]};
    const float* lin_W = (const float*)d_in[18];
    const float* lin_b = (const float*)d_in[19];
    float* out = (float*)d_out;

    char* p = (char*)d_ws;
    auto alloc = [&](size_t bytes) {
        char* r = p;
        p += (bytes + 255) & ~(size_t)255;
        return r;
    };
    int*   deg    = (int*)alloc((size_t)NN * 4);
    int*   offs   = (int*)alloc((size_t)NN * 4);
    int*   cursor = (int*)alloc((size_t)NN * 4);
    float* dinv   = (float*)alloc((size_t)NN * 4);
    int*   eidx   = (int*)alloc((size_t)NE * 4);
    float* Bself  = (float*)alloc(256 * 4);
    unsigned int* ctr = (unsigned int*)alloc(64 * 4);
    float* h_buf  = (float*)alloc(2 * NB * 256 * 4);
    float* hT     = (float*)alloc(3 * NB * 256 * 4);
    float* node   = (float*)alloc((size_t)NN * DOUT * 4);
    float* yA     = (float*)alloc((size_t)NN * DOUT * 4);
    float* yB     = (float*)alloc((size_t)NN * DOUT * 4);
    float* xp     = (float*)alloc((size_t)NN * G3 * 4);
    float* Ax     = xp;   // alias: Ax dead before xp is first written

    // --- GCN ---
    hipMemsetAsync(cursor, 0, (size_t)NN * 4, stream);
    k_init_deg<<<NN / 256, 256, 0, stream>>>(deg);
    k_count<<<NE / 256, 256, 0, stream>>>(ei, deg);
    k_scan_offs<<<1, 1024, 0, stream>>>(deg, offs, dinv);
    k_fill<<<NE / 256, 256, 0, stream>>>(ei, offs, cursor, eidx);
    k_bself<<<1, 256, 0, stream>>>(WB, Bself);
    {
        dim3 g(NN / 128, 256 / 128);
        k_gemm<<<g, 256, 0, stream>>>(x, WA, nullptr, Ax, NN, 256);
    }
    k_gcn<<<NN, 256, 0, stream>>>(Ax, WB, edge_attr, ei, eidx, offs, deg, dinv,
                                  Bself, gcn_bias, node);

    // --- GRU x3 ---
    const float* in_seq = node;
    float* y_outs[3] = {yA, yB, yA};
    for (int l = 0; l < 3; ++l) {
        dim3 g(NN / 128, G3 / 128);
        k_gemm<<<g, 256, 0, stream>>>(in_seq, w_ih[l], b_ih[l], xp, NN, G3);
        hipMemsetAsync(h_buf, 0, 2 * NB * 256 * 4, stream);
        hipMemsetAsync(ctr, 0, 64 * 4, stream);
        k_gru_scan<<<256, 256, 0, stream>>>(xp, w_hh[l], b_hh[l], y_outs[l],
                                            hT + l * NB * 256, h_buf, ctr);
        in_seq = y_outs[l];
    }

    // --- pool + linear + softmax ---
    k_final<<<NB, 256, 0, stream>>>(yA, hT, lin_W, lin_b, out);
}